// Round 9
// baseline (660.751 us; speedup 1.0000x reference)
//
#include <hip/hip_runtime.h>
#include <hip/hip_bf16.h>
#include <cstdint>

#define HW 4096
#define MGc 48
#define RECc 5

typedef __attribute__((ext_vector_type(8))) short bf16x8;
typedef __attribute__((ext_vector_type(4))) float f32x4;

__device__ __forceinline__ float sigf(float x) { return 1.f / (1.f + expf(-x)); }
__device__ __forceinline__ float leakyf(float x) { return x >= 0.f ? x : 0.2f * x; }
__device__ __forceinline__ unsigned short f2bfu(float f) {
  __hip_bfloat16 b = __float2bfloat16(f);
  return *reinterpret_cast<unsigned short*>(&b);
}
__device__ __forceinline__ float bfu2f(unsigned short u) {
  unsigned v = ((unsigned)u) << 16;
  return __uint_as_float(v);
}
__device__ __forceinline__ void gload_lds16(const void* g, void* l) {
  __builtin_amdgcn_global_load_lds(
      (const __attribute__((address_space(1))) unsigned int*)g,
      (__attribute__((address_space(3))) unsigned int*)l, 16, 0, 0);
}

// ---------------- L1: k_att = rm_sum [0,15360) + q_part [15360,16384) ----------------
__global__ __launch_bounds__(256) void k_att(const float* __restrict__ rm,
    float* __restrict__ rm_sum, const float* __restrict__ c,
    const float* __restrict__ ccw, const float* __restrict__ ccb,
    float* __restrict__ q_part) {
  __shared__ __align__(16) char smem[13568];
  int bid = blockIdx.x, tid = threadIdx.x;
  if (bid < 15360) {
    float* sred = (float*)smem;
    int row = bid;
    const float4* p = reinterpret_cast<const float4*>(rm + (size_t)row * 1024);
    float4 v = p[tid];
    float s = v.x + v.y + v.z + v.w;
    #pragma unroll
    for (int off = 32; off; off >>= 1) s += __shfl_down(s, off);
    if ((tid & 63) == 0) sred[tid >> 6] = s;
    __syncthreads();
    if (tid == 0) rm_sum[row] = sred[0] + sred[1] + sred[2] + sred[3];
  } else {
    float* wl = (float*)smem;                 // 3072 f
    float* bl = wl + MGc * 64;                // 48 (+pad)
    float (*red)[MGc] = (float(*)[MGc])(bl + 64);
    int r = bid - 15360;
    int seg = r & 15, b = r >> 4;
    for (int i = tid; i < MGc * 64; i += 256) wl[i] = ccw[i];
    if (tid < MGc) bl[tid] = ccb[tid];
    __syncthreads();
    int px = seg * 256 + tid;
    float acc[MGc];
    #pragma unroll
    for (int m = 0; m < MGc; m++) acc[m] = 0.f;
    const float* cp = c + (size_t)b * 64 * HW + px;
    for (int ci = 0; ci < 64; ci++) {
      float v = cp[(size_t)ci * HW];
      #pragma unroll
      for (int m = 0; m < MGc; m++) acc[m] += wl[m * 64 + ci] * v;
    }
    int lane = tid & 63, wv = tid >> 6;
    #pragma unroll
    for (int m = 0; m < MGc; m++) {
      float t2 = leakyf(acc[m] + bl[m]);
      #pragma unroll
      for (int off = 32; off; off >>= 1) t2 += __shfl_down(t2, off);
      if (lane == 0) red[wv][m] = t2;
    }
    __syncthreads();
    if (tid < MGc) {
      float t2 = red[0][tid] + red[1][tid] + red[2][tid] + red[3][tid];
      q_part[((size_t)b * 16 + seg) * MGc + tid] = t2;
    }
  }
}

// ---------------- L2: k_mid = mt_pre [0,12288) + wpack [12288,13728) +
//                  Pp border [13728,14768) + ppack [14768,22960) ----------------
__global__ __launch_bounds__(256) void k_mid(const float* __restrict__ rm,
    const float* __restrict__ rm_sum, const float* __restrict__ q_part,
    float* __restrict__ mt_pre, const float* __restrict__ cw,
    __hip_bfloat16* __restrict__ Wp, __hip_bfloat16* __restrict__ Pp,
    const float* __restrict__ xin, const float* __restrict__ hin) {
  __shared__ __align__(16) char smem[16704];
  int bid = blockIdx.x, tid = threadIdx.x;
  if (bid < 12288) {
    // ---- mt_pre (attn computed per block)
    float* sat = (float*)smem;
    int idx = bid * 256 + tid;
    int b = idx / (MGc * 1024);
    if (tid < 64) {
      int lane = tid;
      float q = 0.f;
      if (lane < MGc) {
        float s = 0.f;
        for (int sg = 0; sg < 16; sg++) s += q_part[((size_t)b * 16 + sg) * MGc + lane];
        q = s * (1.f / 4096.f);
      }
      float qs = q * q;
      #pragma unroll
      for (int off = 32; off; off >>= 1) qs += __shfl_xor(qs, off);
      float qn = fmaxf(sqrtf(qs), 1e-8f);
      float cosv[RECc];
      #pragma unroll
      for (int r = 0; r < RECc; r++) {
        float m = 0.f;
        if (lane < MGc) m = rm_sum[((size_t)b * RECc + r) * MGc + lane] * (1.f / 1024.f);
        float d = q * m, ms = m * m;
        #pragma unroll
        for (int off = 32; off; off >>= 1) { d += __shfl_xor(d, off); ms += __shfl_xor(ms, off); }
        float mn = fmaxf(sqrtf(ms), 1e-8f);
        cosv[r] = d / (qn * mn);
      }
      float mx = cosv[0];
      #pragma unroll
      for (int r = 1; r < RECc; r++) mx = fmaxf(mx, cosv[r]);
      float ssum = 0.f;
      #pragma unroll
      for (int r = 0; r < RECc; r++) { cosv[r] = expf(cosv[r] - mx); ssum += cosv[r]; }
      float inv = 1.f / ssum;
      #pragma unroll
      for (int r = 0; r < RECc; r++)
        if (lane == r) sat[r] = cosv[r] * inv;
    }
    __syncthreads();
    int rem = idx - b * (MGc * 1024);
    const float* base = rm + (size_t)b * RECc * MGc * 1024 + rem;
    float v = sat[0] * base[0] + sat[1] * base[MGc * 1024] + sat[2] * base[2 * MGc * 1024]
            + sat[3] * base[3 * MGc * 1024] + sat[4] * base[4 * MGc * 1024];
    mt_pre[idx] = v;
  } else if (bid < 13728) {
    // ---- wpack
    int idx = (bid - 12288) * 256 + tid;
    int t = idx / (320 * 128);
    int rem = idx % (320 * 128);
    int ocp = rem / 128, ci = rem % 128;
    int nt = ocp / 80, r2 = ocp % 80, gate = r2 / 16, ml = r2 % 16;
    int oc = gate * 64 + nt * 16 + ml;
    Wp[idx] = __float2bfloat16(cw[((size_t)oc * 128 + ci) * 9 + t]);
  } else if (bid < 14768) {
    // ---- Pp border zero
    int idx = (bid - 13728) * 256 + tid;
    int b = idx / 4160, i = idx % 4160;
    bf16x8* base = reinterpret_cast<bf16x8*>(Pp);
    size_t u;
    if (i < 2112) {
      int r = (i < 1056) ? 0 : 65;
      int j = (i < 1056) ? i : i - 1056;
      u = ((size_t)b * 66 + r) * 1056 + j;
    } else {
      int i2 = i - 2112;
      int row = 1 + (i2 >> 5), k = i2 & 31;
      int px = (k < 16) ? 0 : 65, ci8 = k & 15;
      u = (((size_t)b * 66 + row) * 66 + px) * 16 + ci8;
    }
    base[u] = (bf16x8)0;
  } else {
    // ---- ppack
    float (*t)[65] = (float(*)[65])smem;
    int r = bid - 14768;
    int half = r & 1, y = (r >> 1) & 63, b = r >> 7;
    const float* src = (half ? hin : xin) + (size_t)b * 64 * HW + y * 64;
    #pragma unroll
    for (int it = 0; it < 4; it++) {
      int li = it * 256 + tid;
      int ci = li >> 4, x4 = (li & 15) * 4;
      float4 v = *reinterpret_cast<const float4*>(src + (size_t)ci * HW + x4);
      t[x4][ci] = v.x; t[x4 + 1][ci] = v.y; t[x4 + 2][ci] = v.z; t[x4 + 3][ci] = v.w;
    }
    __syncthreads();
    int x = tid >> 2, c16 = (tid & 3) * 16;
    unsigned short* dst = reinterpret_cast<unsigned short*>(Pp) +
        ((((size_t)b * 66 + y + 1) * 66 + x + 1) * 128 + half * 64 + c16);
    bf16x8 o0, o1;
    #pragma unroll
    for (int j = 0; j < 8; j++) {
      o0[j] = (short)f2bfu(t[x][c16 + j]);
      o1[j] = (short)f2bfu(t[x][c16 + 8 + j]);
    }
    *reinterpret_cast<bf16x8*>(dst) = o0;
    *reinterpret_cast<bf16x8*>(dst + 8) = o1;
  }
}

// ---------------- L3: k_main = gates MFMA [0,4096) + ssm [4096,4608) ----------------
// Gates: 512 thr (8 waves), tile 16x16 px x 80 oc; wave owns 2 rows (acc[2][5]=40 AGPR)
// -> 4 waves/SIMD, 2 blocks/CU (LDS 66.8KB). ssm blocks fill gates' drain tail.
__global__ __launch_bounds__(512, 4) void k_main(
    const __hip_bfloat16* __restrict__ Pp, const __hip_bfloat16* __restrict__ Wp,
    const float* __restrict__ c, const float* __restrict__ cb,
    float* __restrict__ c_new, __hip_bfloat16* __restrict__ o_g,
    __hip_bfloat16* __restrict__ lam_g,
    const float* __restrict__ mt_pre, const float* __restrict__ sw,
    const float* __restrict__ sb, __hip_bfloat16* __restrict__ mt) {
  __shared__ __align__(16) char arena[66816];
  int bid = blockIdx.x, tid = threadIdx.x;
  if (bid < 4096) {
    // ================= gates =================
    bf16x8* s_in = (bf16x8*)arena;            // 1296 units (L*4+lq)*18+xi : 20736 B
    bf16x8* s_w  = (bf16x8*)(arena + 20736);  // 2880 units (t*4+g)*80+ol  : 46080 B
    int t_id = (bid & 7) * 512 + (bid >> 3);  // bijective XCD swizzle
    int b = t_id >> 6;
    int r6 = t_id & 63;
    int ytile = r6 >> 4, xtile = (r6 >> 2) & 3, nt = r6 & 3;
    int y0 = ytile * 16, x0 = xtile * 16;
    int wv = tid >> 6, lane = tid & 63;
    int lane15 = lane & 15, lq = lane >> 4;

    const char* Pb = (const char*)Pp;
    const char* Wb = (const char*)Wp;

    // precompute staging addresses (cc-invariant)
    const char* gin[3]; int din[3]; bool ain[3];
    #pragma unroll
    for (int k = 0; k < 3; k++) {
      int u = wv + 8 * k;
      int e = u * 64 + lane;
      ain[k] = (e < 1296);
      int ee = (e < 1296) ? e : 0;
      int L = ee / 72, r = ee - L * 72;
      int llq = r / 18, xi = r - llq * 18;
      gin[k] = Pb + ((((size_t)b * 66 + y0 + L) * 66 + (x0 + xi)) * 256) + llq * 16;
      din[k] = ee;
    }
    const char* gw[6]; int dw[6]; bool aw[6];
    #pragma unroll
    for (int k = 0; k < 6; k++) {
      int u = wv + 8 * k;
      aw[k] = (u < 45);
      int uu = aw[k] ? u : 0;
      int e = uu * 64 + lane;
      int unit = e / 80, ol = e - unit * 80;
      int t = unit >> 2, g = unit & 3;
      gw[k] = Wb + (((size_t)t * 320 + nt * 80 + ol) * 128 + g * 8) * 2;
      dw[k] = e;
    }

    f32x4 acc[2][5];
    #pragma unroll
    for (int i = 0; i < 2; i++)
      #pragma unroll
      for (int j = 0; j < 5; j++) acc[i][j] = (f32x4)0.f;

    #pragma unroll 1
    for (int cc = 0; cc < 4; cc++) {
      __syncthreads();
      int co = cc * 64;
      #pragma unroll
      for (int k = 0; k < 3; k++)
        if (ain[k]) gload_lds16(gin[k] + co, (void*)&s_in[din[k]]);
      #pragma unroll
      for (int k = 0; k < 6; k++)
        if (aw[k]) gload_lds16(gw[k] + co, (void*)&s_w[dw[k]]);
      __syncthreads();

      #pragma unroll
      for (int dx = 0; dx < 3; dx++) {
        bf16x8 af[4];
        #pragma unroll
        for (int r = 0; r < 4; r++)
          af[r] = s_in[((wv * 2 + r) * 4 + lq) * 18 + lane15 + dx];
        #pragma unroll
        for (int ky = 0; ky < 3; ky++) {
          int t = ky * 3 + dx;
          bf16x8 bw[5];
          #pragma unroll
          for (int gg = 0; gg < 5; gg++)
            bw[gg] = s_w[(t * 4 + lq) * 80 + gg * 16 + lane15];
          __builtin_amdgcn_s_setprio(1);
          #pragma unroll
          for (int rr = 0; rr < 2; rr++)
            #pragma unroll
            for (int gg = 0; gg < 5; gg++)
              acc[rr][gg] = __builtin_amdgcn_mfma_f32_16x16x32_bf16(
                  af[rr + ky], bw[gg], acc[rr][gg], 0, 0, 0);
          __builtin_amdgcn_s_setprio(0);
        }
      }
    }

    // fused LSTM pointwise epilogue
    int m_hid = nt * 16 + lane15;
    float bi = cb[m_hid], bff = cb[64 + m_hid], bgg = cb[128 + m_hid],
          bo = cb[192 + m_hid], bl = cb[256 + m_hid];
    int xb = x0 + lq * 4;
    size_t chofs = ((size_t)b * 64 + m_hid) * HW;
    #pragma unroll
    for (int rr = 0; rr < 2; rr++) {
      int y = y0 + wv * 2 + rr;
      size_t pofs = chofs + (size_t)y * 64 + xb;
      f32x4 cold = *reinterpret_cast<const f32x4*>(c + pofs);
      f32x4 cn;
      unsigned short ov[4], lv[4];
      #pragma unroll
      for (int e = 0; e < 4; e++) {
        float i_ = sigf(acc[rr][0][e] + bi);
        float f_ = sigf(acc[rr][1][e] + bff);
        float g_ = tanhf(acc[rr][2][e] + bgg);
        float o_ = sigf(acc[rr][3][e] + bo);
        float l_ = sigf(acc[rr][4][e] + bl);
        cn[e] = f_ * cold[e] + i_ * g_;
        ov[e] = f2bfu(o_);
        lv[e] = f2bfu(l_);
      }
      *reinterpret_cast<f32x4*>(c_new + pofs) = cn;
      ushort4 ovv = {ov[0], ov[1], ov[2], ov[3]};
      ushort4 lvv = {lv[0], lv[1], lv[2], lv[3]};
      *reinterpret_cast<ushort4*>(reinterpret_cast<unsigned short*>(o_g) + pofs) = ovv;
      *reinterpret_cast<ushort4*>(reinterpret_cast<unsigned short*>(lam_g) + pofs) = lvv;
    }
  } else {
    // ================= ssm: conv_transpose2d 4x4 s2 p1 + leaky -> mt =================
    float (*in_t)[10][20] = (float(*)[10][20])arena;            // 9600 B
    float (*w_t)[48][16]  = (float(*)[48][16])(arena + 9600);   // 36864 B
    int sbid = bid - 4096;
    int tile = sbid & 7, b = sbid >> 3;
    int y0 = (tile >> 1) * 16, x0 = (tile & 1) * 32;
    int wv = tid >> 6, lane = tid & 63;
    int co0 = wv * 6;
    int oyl = lane >> 2, xseg = lane & 3;
    int oy = y0 + oyl;
    int iy0 = (y0 >> 1) - 1, ix0 = (x0 >> 1) - 1;
    int kyA = (oy + 1) & 1;
    int iyA = (oy + 1 - kyA) >> 1;
    int rA = iyA - iy0, rB = rA - 1;
    float acc[6][8] = {};
    for (int ch = 0; ch < 4; ch++) {
      int ci0 = ch * 12;
      __syncthreads();
      for (int i = tid; i < 12 * 10 * 18; i += 512) {
        int ci = i / 180, rr = (i % 180) / 18, cc2 = i % 18;
        int giy = iy0 + rr, gix = ix0 + cc2;
        float v = 0.f;
        if ((unsigned)giy < 32u && (unsigned)gix < 32u)
          v = mt_pre[(((size_t)b * MGc + ci0 + ci) * 32 + giy) * 32 + gix];
        in_t[ci][rr][cc2] = v;
      }
      for (int i = tid; i < 12 * 48 * 16; i += 512)
        (&w_t[0][0][0])[i] = sw[ci0 * 768 + i];
      __syncthreads();
      #pragma unroll 1
      for (int ci = 0; ci < 12; ci++) {
        float4 a0 = *reinterpret_cast<const float4*>(&in_t[ci][rA][xseg * 4]);
        float4 a1 = *reinterpret_cast<const float4*>(&in_t[ci][rA][xseg * 4 + 4]);
        float4 b0 = *reinterpret_cast<const float4*>(&in_t[ci][rB][xseg * 4]);
        float4 b1 = *reinterpret_cast<const float4*>(&in_t[ci][rB][xseg * 4 + 4]);
        float vA[6] = {a0.x, a0.y, a0.z, a0.w, a1.x, a1.y};
        float vB[6] = {b0.x, b0.y, b0.z, b0.w, b1.x, b1.y};
        #pragma unroll
        for (int co = 0; co < 6; co++) {
          const float* wp = &w_t[ci][co0 + co][0];
          float4 wA = *reinterpret_cast<const float4*>(wp + kyA * 4);
          float4 wB = *reinterpret_cast<const float4*>(wp + (kyA + 2) * 4);
          #pragma unroll
          for (int j = 0; j < 8; j++) {
            if ((j & 1) == 0) {
              int hi = (j >> 1) + 1, lo = j >> 1;
              acc[co][j] += vA[hi] * wA.y + vA[lo] * wA.w + vB[hi] * wB.y + vB[lo] * wB.w;
            } else {
              int hi = ((j + 1) >> 1) + 1, lo = (j + 1) >> 1;
              acc[co][j] += vA[hi] * wA.x + vA[lo] * wA.z + vB[hi] * wB.x + vB[lo] * wB.z;
            }
          }
        }
      }
    }
    int oxb = x0 + xseg * 8;
    #pragma unroll
    for (int co = 0; co < 6; co++) {
      float bb = sb[co0 + co];
      size_t obase = (((size_t)b * MGc + co0 + co) * 64 + oy) * 64 + oxb;
      #pragma unroll
      for (int j = 0; j < 8; j++)
        mt[obase + j] = __float2bfloat16(leakyf(acc[co][j] + bb));
    }
  }
}

// ---------------- L4: k_fuse: convfuse 1x1 + tanh + blend -> h_out ----------------
__global__ __launch_bounds__(256) void k_fuse(const float* __restrict__ c_new,
    const __hip_bfloat16* __restrict__ mt, const __hip_bfloat16* __restrict__ o_g,
    const __hip_bfloat16* __restrict__ lam_g, const float* __restrict__ h,
    const float* __restrict__ fw, const float* __restrict__ fb,
    float* __restrict__ h_out) {
  __shared__ float wl[112][64];
  int b = blockIdx.y, seg = blockIdx.x;  // 8 segs of 512 px
  for (int i = threadIdx.x; i < 112 * 64; i += 256) {
    int ci = i >> 6, co = i & 63;
    wl[ci][co] = fw[co * 112 + ci];
  }
  __syncthreads();
  int px = seg * 512 + threadIdx.x * 2;
  size_t bofs = (size_t)b * 64 * HW;
  float2 acc[64];
  #pragma unroll
  for (int co = 0; co < 64; co++) { float bv = fb[co]; acc[co].x = bv; acc[co].y = bv; }
  #pragma unroll 1
  for (int ci = 0; ci < 64; ci++) {
    float2 v = *reinterpret_cast<const float2*>(c_new + bofs + (size_t)ci * HW + px);
    #pragma unroll
    for (int c4 = 0; c4 < 16; c4++) {
      float4 w = *reinterpret_cast<const float4*>(&wl[ci][c4 * 4]);
      acc[c4 * 4 + 0].x += w.x * v.x; acc[c4 * 4 + 0].y += w.x * v.y;
      acc[c4 * 4 + 1].x += w.y * v.x; acc[c4 * 4 + 1].y += w.y * v.y;
      acc[c4 * 4 + 2].x += w.z * v.x; acc[c4 * 4 + 2].y += w.z * v.y;
      acc[c4 * 4 + 3].x += w.w * v.x; acc[c4 * 4 + 3].y += w.w * v.y;
    }
  }
  const unsigned short* mtu = reinterpret_cast<const unsigned short*>(mt);
  size_t mtofs = (size_t)b * MGc * HW + px;
  #pragma unroll 1
  for (int ci = 0; ci < 48; ci++) {
    unsigned u = *reinterpret_cast<const unsigned*>(mtu + mtofs + (size_t)ci * HW);
    float vx = bfu2f((unsigned short)(u & 0xffff));
    float vy = bfu2f((unsigned short)(u >> 16));
    #pragma unroll
    for (int c4 = 0; c4 < 16; c4++) {
      float4 w = *reinterpret_cast<const float4*>(&wl[64 + ci][c4 * 4]);
      acc[c4 * 4 + 0].x += w.x * vx; acc[c4 * 4 + 0].y += w.x * vy;
      acc[c4 * 4 + 1].x += w.y * vx; acc[c4 * 4 + 1].y += w.y * vy;
      acc[c4 * 4 + 2].x += w.z * vx; acc[c4 * 4 + 2].y += w.z * vy;
      acc[c4 * 4 + 3].x += w.w * vx; acc[c4 * 4 + 3].y += w.w * vy;
    }
  }
  const unsigned short* ou = reinterpret_cast<const unsigned short*>(o_g);
  const unsigned short* lu = reinterpret_cast<const unsigned short*>(lam_g);
  #pragma unroll
  for (int co = 0; co < 64; co++) {
    size_t ofs = bofs + (size_t)co * HW + px;
    unsigned uo = *reinterpret_cast<const unsigned*>(ou + ofs);
    unsigned ul = *reinterpret_cast<const unsigned*>(lu + ofs);
    float2 hv = *reinterpret_cast<const float2*>(h + ofs);
    float hnx = tanhf(acc[co].x), hny = tanhf(acc[co].y);
    float ox = bfu2f((unsigned short)(uo & 0xffff)), oy = bfu2f((unsigned short)(uo >> 16));
    float lx = bfu2f((unsigned short)(ul & 0xffff)), ly = bfu2f((unsigned short)(ul >> 16));
    float2 r;
    r.x = lx * (ox * hnx) + (1.f - lx) * hv.x;
    r.y = ly * (oy * hny) + (1.f - ly) * hv.y;
    *reinterpret_cast<float2*>(h_out + ofs) = r;
  }
}

extern "C" void kernel_launch(void* const* d_in, const int* in_sizes, int n_in,
                              void* d_out, int out_size, void* d_ws, size_t ws_size,
                              hipStream_t stream) {
  const float* x   = (const float*)d_in[0];
  const float* h   = (const float*)d_in[1];
  const float* c   = (const float*)d_in[2];
  const float* rm  = (const float*)d_in[3];
  const float* cw  = (const float*)d_in[4];
  const float* cb  = (const float*)d_in[5];
  const float* ccw = (const float*)d_in[6];
  const float* ccb = (const float*)d_in[7];
  const float* sw  = (const float*)d_in[8];
  const float* sb  = (const float*)d_in[9];
  const float* fw  = (const float*)d_in[10];
  const float* fb  = (const float*)d_in[11];

  float* h_out = (float*)d_out;
  float* c_new = h_out + (size_t)16777216;

  // Workspace (lifetime-aliased):
  //   rm_sum [0..61440) + q_part [65536..262144): live L1->L2 only
  //   o_g [0..33554432): born L3 (after L2 reads finish; stream-ordered) ALIASES above
  //   lam_g [33554432..67108864) | mt [67108864..92274688)
  //   Pp [92274688..163643392) | Wp [163643392..164380672)
  //   mt_pre -> d_out h_out region [0..12582912): dead before k_fuse writes h_out.
  char* ws = (char*)d_ws;
  float* rm_sum = (float*)(ws + 0);
  float* q_part = (float*)(ws + 65536);
  __hip_bfloat16* o_g   = (__hip_bfloat16*)(ws + 0);
  __hip_bfloat16* lam_g = (__hip_bfloat16*)(ws + 33554432);
  __hip_bfloat16* mt    = (__hip_bfloat16*)(ws + 67108864);
  __hip_bfloat16* Pp    = (__hip_bfloat16*)(ws + 92274688);
  __hip_bfloat16* Wp    = (__hip_bfloat16*)(ws + 163643392);
  float* mt_pre = h_out;  // d_out[0..12.6MB): free until k_fuse

  k_att<<<16384, 256, 0, stream>>>(rm, rm_sum, c, ccw, ccb, q_part);
  k_mid<<<22960, 256, 0, stream>>>(rm, rm_sum, q_part, mt_pre, cw, Wp, Pp, x, h);
  k_main<<<4608, 512, 0, stream>>>(Pp, Wp, c, cb, c_new, o_g, lam_g, mt_pre, sw, sb, mt);
  k_fuse<<<dim3(8, 64), 256, 0, stream>>>(c_new, mt, o_g, lam_g, h, fw, fb, h_out);
}

// Round 10
// 641.431 us; speedup vs baseline: 1.0301x; 1.0301x over previous
//
#include <hip/hip_runtime.h>
#include <hip/hip_bf16.h>
#include <cstdint>

#define HW 4096
#define MGc 48
#define RECc 5

typedef __attribute__((ext_vector_type(8))) short bf16x8;
typedef __attribute__((ext_vector_type(4))) float f32x4;

__device__ __forceinline__ float sigf(float x) { return 1.f / (1.f + expf(-x)); }
__device__ __forceinline__ float leakyf(float x) { return x >= 0.f ? x : 0.2f * x; }
__device__ __forceinline__ unsigned short f2bfu(float f) {
  __hip_bfloat16 b = __float2bfloat16(f);
  return *reinterpret_cast<unsigned short*>(&b);
}
__device__ __forceinline__ float bfu2f(unsigned short u) {
  unsigned v = ((unsigned)u) << 16;
  return __uint_as_float(v);
}
__device__ __forceinline__ void gload_lds16(const void* g, void* l) {
  __builtin_amdgcn_global_load_lds(
      (const __attribute__((address_space(1))) unsigned int*)g,
      (__attribute__((address_space(3))) unsigned int*)l, 16, 0, 0);
}

// ---------------- L1: k_att = rm_sum [0,15360) + q_part [15360,16384) ----------------
__global__ __launch_bounds__(256) void k_att(const float* __restrict__ rm,
    float* __restrict__ rm_sum, const float* __restrict__ c,
    const float* __restrict__ ccw, const float* __restrict__ ccb,
    float* __restrict__ q_part) {
  __shared__ __align__(16) char smem[13568];
  int bid = blockIdx.x, tid = threadIdx.x;
  if (bid < 15360) {
    float* sred = (float*)smem;
    int row = bid;
    const float4* p = reinterpret_cast<const float4*>(rm + (size_t)row * 1024);
    float4 v = p[tid];
    float s = v.x + v.y + v.z + v.w;
    #pragma unroll
    for (int off = 32; off; off >>= 1) s += __shfl_down(s, off);
    if ((tid & 63) == 0) sred[tid >> 6] = s;
    __syncthreads();
    if (tid == 0) rm_sum[row] = sred[0] + sred[1] + sred[2] + sred[3];
  } else {
    float* wl = (float*)smem;
    float* bl = wl + MGc * 64;
    float (*red)[MGc] = (float(*)[MGc])(bl + 64);
    int r = bid - 15360;
    int seg = r & 15, b = r >> 4;
    for (int i = tid; i < MGc * 64; i += 256) wl[i] = ccw[i];
    if (tid < MGc) bl[tid] = ccb[tid];
    __syncthreads();
    int px = seg * 256 + tid;
    float acc[MGc];
    #pragma unroll
    for (int m = 0; m < MGc; m++) acc[m] = 0.f;
    const float* cp = c + (size_t)b * 64 * HW + px;
    for (int ci = 0; ci < 64; ci++) {
      float v = cp[(size_t)ci * HW];
      #pragma unroll
      for (int m = 0; m < MGc; m++) acc[m] += wl[m * 64 + ci] * v;
    }
    int lane = tid & 63, wv = tid >> 6;
    #pragma unroll
    for (int m = 0; m < MGc; m++) {
      float t2 = leakyf(acc[m] + bl[m]);
      #pragma unroll
      for (int off = 32; off; off >>= 1) t2 += __shfl_down(t2, off);
      if (lane == 0) red[wv][m] = t2;
    }
    __syncthreads();
    if (tid < MGc) {
      float t2 = red[0][tid] + red[1][tid] + red[2][tid] + red[3][tid];
      q_part[((size_t)b * 16 + seg) * MGc + tid] = t2;
    }
  }
}

// ---------------- L2: k_mid = mt_pre [0,12288) + wpack [12288,13728) +
//                  Pp border [13728,14768) + ppack [14768,22960) ----------------
__global__ __launch_bounds__(256) void k_mid(const float* __restrict__ rm,
    const float* __restrict__ rm_sum, const float* __restrict__ q_part,
    float* __restrict__ mt_pre, const float* __restrict__ cw,
    __hip_bfloat16* __restrict__ Wp, __hip_bfloat16* __restrict__ Pp,
    const float* __restrict__ xin, const float* __restrict__ hin) {
  __shared__ __align__(16) char smem[16704];
  int bid = blockIdx.x, tid = threadIdx.x;
  if (bid < 12288) {
    float* sat = (float*)smem;
    int idx = bid * 256 + tid;
    int b = idx / (MGc * 1024);
    if (tid < 64) {
      int lane = tid;
      float q = 0.f;
      if (lane < MGc) {
        float s = 0.f;
        for (int sg = 0; sg < 16; sg++) s += q_part[((size_t)b * 16 + sg) * MGc + lane];
        q = s * (1.f / 4096.f);
      }
      float qs = q * q;
      #pragma unroll
      for (int off = 32; off; off >>= 1) qs += __shfl_xor(qs, off);
      float qn = fmaxf(sqrtf(qs), 1e-8f);
      float cosv[RECc];
      #pragma unroll
      for (int r = 0; r < RECc; r++) {
        float m = 0.f;
        if (lane < MGc) m = rm_sum[((size_t)b * RECc + r) * MGc + lane] * (1.f / 1024.f);
        float d = q * m, ms = m * m;
        #pragma unroll
        for (int off = 32; off; off >>= 1) { d += __shfl_xor(d, off); ms += __shfl_xor(ms, off); }
        float mn = fmaxf(sqrtf(ms), 1e-8f);
        cosv[r] = d / (qn * mn);
      }
      float mx = cosv[0];
      #pragma unroll
      for (int r = 1; r < RECc; r++) mx = fmaxf(mx, cosv[r]);
      float ssum = 0.f;
      #pragma unroll
      for (int r = 0; r < RECc; r++) { cosv[r] = expf(cosv[r] - mx); ssum += cosv[r]; }
      float inv = 1.f / ssum;
      #pragma unroll
      for (int r = 0; r < RECc; r++)
        if (lane == r) sat[r] = cosv[r] * inv;
    }
    __syncthreads();
    int rem = idx - b * (MGc * 1024);
    const float* base = rm + (size_t)b * RECc * MGc * 1024 + rem;
    float v = sat[0] * base[0] + sat[1] * base[MGc * 1024] + sat[2] * base[2 * MGc * 1024]
            + sat[3] * base[3 * MGc * 1024] + sat[4] * base[4 * MGc * 1024];
    mt_pre[idx] = v;
  } else if (bid < 13728) {
    int idx = (bid - 12288) * 256 + tid;
    int t = idx / (320 * 128);
    int rem = idx % (320 * 128);
    int ocp = rem / 128, ci = rem % 128;
    int nt = ocp / 80, r2 = ocp % 80, gate = r2 / 16, ml = r2 % 16;
    int oc = gate * 64 + nt * 16 + ml;
    Wp[idx] = __float2bfloat16(cw[((size_t)oc * 128 + ci) * 9 + t]);
  } else if (bid < 14768) {
    int idx = (bid - 13728) * 256 + tid;
    int b = idx / 4160, i = idx % 4160;
    bf16x8* base = reinterpret_cast<bf16x8*>(Pp);
    size_t u;
    if (i < 2112) {
      int r = (i < 1056) ? 0 : 65;
      int j = (i < 1056) ? i : i - 1056;
      u = ((size_t)b * 66 + r) * 1056 + j;
    } else {
      int i2 = i - 2112;
      int row = 1 + (i2 >> 5), k = i2 & 31;
      int px = (k < 16) ? 0 : 65, ci8 = k & 15;
      u = (((size_t)b * 66 + row) * 66 + px) * 16 + ci8;
    }
    base[u] = (bf16x8)0;
  } else {
    float (*t)[65] = (float(*)[65])smem;
    int r = bid - 14768;
    int half = r & 1, y = (r >> 1) & 63, b = r >> 7;
    const float* src = (half ? hin : xin) + (size_t)b * 64 * HW + y * 64;
    #pragma unroll
    for (int it = 0; it < 4; it++) {
      int li = it * 256 + tid;
      int ci = li >> 4, x4 = (li & 15) * 4;
      float4 v = *reinterpret_cast<const float4*>(src + (size_t)ci * HW + x4);
      t[x4][ci] = v.x; t[x4 + 1][ci] = v.y; t[x4 + 2][ci] = v.z; t[x4 + 3][ci] = v.w;
    }
    __syncthreads();
    int x = tid >> 2, c16 = (tid & 3) * 16;
    unsigned short* dst = reinterpret_cast<unsigned short*>(Pp) +
        ((((size_t)b * 66 + y + 1) * 66 + x + 1) * 128 + half * 64 + c16);
    bf16x8 o0, o1;
    #pragma unroll
    for (int j = 0; j < 8; j++) {
      o0[j] = (short)f2bfu(t[x][c16 + j]);
      o1[j] = (short)f2bfu(t[x][c16 + 8 + j]);
    }
    *reinterpret_cast<bf16x8*>(dst) = o0;
    *reinterpret_cast<bf16x8*>(dst + 8) = o1;
  }
}

// ---------------- K5: conv_transpose2d 4x4 s2 p1 + leaky -> mt (bf16) ----------
__global__ __launch_bounds__(512) void k_ssm(const float* __restrict__ mt_pre,
    const float* __restrict__ w, const float* __restrict__ bias,
    __hip_bfloat16* __restrict__ mt) {
  __shared__ float in_t[12][10][20];
  __shared__ float w_t[12][48][16];
  int b = blockIdx.y;
  int tile = blockIdx.x;
  int y0 = (tile >> 1) * 16, x0 = (tile & 1) * 32;
  int wv = threadIdx.x >> 6, lane = threadIdx.x & 63;
  int co0 = wv * 6;
  int oyl = lane >> 2, xseg = lane & 3;
  int oy = y0 + oyl;
  int iy0 = (y0 >> 1) - 1, ix0 = (x0 >> 1) - 1;
  int kyA = (oy + 1) & 1;
  int iyA = (oy + 1 - kyA) >> 1;
  int rA = iyA - iy0, rB = rA - 1;
  float acc[6][8] = {};
  for (int ch = 0; ch < 4; ch++) {
    int ci0 = ch * 12;
    __syncthreads();
    for (int i = threadIdx.x; i < 12 * 10 * 18; i += 512) {
      int ci = i / 180, rr = (i % 180) / 18, cc2 = i % 18;
      int giy = iy0 + rr, gix = ix0 + cc2;
      float v = 0.f;
      if ((unsigned)giy < 32u && (unsigned)gix < 32u)
        v = mt_pre[(((size_t)b * MGc + ci0 + ci) * 32 + giy) * 32 + gix];
      in_t[ci][rr][cc2] = v;
    }
    for (int i = threadIdx.x; i < 12 * 48 * 16; i += 512)
      (&w_t[0][0][0])[i] = w[ci0 * 768 + i];
    __syncthreads();
    #pragma unroll 1
    for (int ci = 0; ci < 12; ci++) {
      float4 a0 = *reinterpret_cast<const float4*>(&in_t[ci][rA][xseg * 4]);
      float4 a1 = *reinterpret_cast<const float4*>(&in_t[ci][rA][xseg * 4 + 4]);
      float4 b0 = *reinterpret_cast<const float4*>(&in_t[ci][rB][xseg * 4]);
      float4 b1 = *reinterpret_cast<const float4*>(&in_t[ci][rB][xseg * 4 + 4]);
      float vA[6] = {a0.x, a0.y, a0.z, a0.w, a1.x, a1.y};
      float vB[6] = {b0.x, b0.y, b0.z, b0.w, b1.x, b1.y};
      #pragma unroll
      for (int co = 0; co < 6; co++) {
        const float* wp = &w_t[ci][co0 + co][0];
        float4 wA = *reinterpret_cast<const float4*>(wp + kyA * 4);
        float4 wB = *reinterpret_cast<const float4*>(wp + (kyA + 2) * 4);
        #pragma unroll
        for (int j = 0; j < 8; j++) {
          if ((j & 1) == 0) {
            int hi = (j >> 1) + 1, lo = j >> 1;
            acc[co][j] += vA[hi] * wA.y + vA[lo] * wA.w + vB[hi] * wB.y + vB[lo] * wB.w;
          } else {
            int hi = ((j + 1) >> 1) + 1, lo = (j + 1) >> 1;
            acc[co][j] += vA[hi] * wA.x + vA[lo] * wA.z + vB[hi] * wB.x + vB[lo] * wB.z;
          }
        }
      }
    }
  }
  int oxb = x0 + xseg * 8;
  #pragma unroll
  for (int co = 0; co < 6; co++) {
    float bb = bias[co0 + co];
    size_t obase = (((size_t)b * MGc + co0 + co) * 64 + oy) * 64 + oxb;
    #pragma unroll
    for (int j = 0; j < 8; j++)
      mt[obase + j] = __float2bfloat16(leakyf(acc[co][j] + bb));
  }
}

// ---------------- K6: gates conv3x3 MFMA; 4-wave, 2 blocks/CU, padded s_w ------------
// s_w rows padded 80->81 units (16B): lq-group stride 1296B = 4-bank offset ->
// bw ds_read_b128 conflict-free (was 4-way at stride 1280B).
// Staging keeps LINEAR LDS dest (rule #21): row/col mapping folded into each lane's
// precomputed global source; pad slots (ol==80) source a dummy, never read.
__global__ __launch_bounds__(256) void k_gates_mfma(
    const __hip_bfloat16* __restrict__ Pp, const __hip_bfloat16* __restrict__ Wp,
    const float* __restrict__ c, const float* __restrict__ cb,
    float* __restrict__ c_new, __hip_bfloat16* __restrict__ o_g,
    __hip_bfloat16* __restrict__ lam_g) {
  __shared__ bf16x8 s_in[1296];   // (L*4+lq)*18 + xi : 20736 B
  __shared__ bf16x8 s_w[2944];    // rows of 81: (t*4+g)*81 + ol : 47104 B
  int orig = blockIdx.y * gridDim.x + blockIdx.x;
  int t_id = (orig & 7) * 512 + (orig >> 3);   // bijective, 4096 % 8 == 0
  int b = t_id >> 6;
  int r6 = t_id & 63;
  int ytile = r6 >> 4, xtile = (r6 >> 2) & 3, nt = r6 & 3;
  int y0 = ytile * 16, x0 = xtile * 16;
  int tid = threadIdx.x;
  int wv = tid >> 6, lane = tid & 63;
  int lane15 = lane & 15, lq = lane >> 4;

  const char* Pb = (const char*)Pp;
  const char* Wb = (const char*)Wp;

  // ---- precompute staging addresses (cc-invariant) ----
  const char* gin[6]; int din[6]; bool ain[6];
  #pragma unroll
  for (int k = 0; k < 6; k++) {
    int u = wv + 4 * k;
    int e = u * 64 + lane;
    ain[k] = (u < 21) && (e < 1296);
    int ee = (e < 1296) ? e : 0;
    int L = ee / 72, r = ee - L * 72;
    int llq = r / 18, xi = r - llq * 18;
    gin[k] = Pb + ((((size_t)b * 66 + y0 + L) * 66 + (x0 + xi)) * 256) + llq * 16;
    din[k] = ee;
  }
  const char* gw[12]; int dw[12]; bool aw[12];
  #pragma unroll
  for (int k = 0; k < 12; k++) {
    int u = wv + 4 * k;
    int e = u * 64 + lane;
    aw[k] = (e < 2916);                 // 36 rows x 81
    int ee = aw[k] ? e : 0;
    int row = ee / 81, ol = ee - row * 81;
    if (ol > 79) ol = 0;                // pad slot: dummy source, never read
    int t = row >> 2, g = row & 3;
    gw[k] = Wb + (((size_t)t * 320 + nt * 80 + ol) * 128 + g * 8) * 2;
    dw[k] = ee;
  }

  f32x4 acc[4][5];
  #pragma unroll
  for (int i = 0; i < 4; i++)
    #pragma unroll
    for (int j = 0; j < 5; j++) acc[i][j] = (f32x4)0.f;

  #pragma unroll 1
  for (int cc = 0; cc < 4; cc++) {
    __syncthreads();
    int co = cc * 64;
    #pragma unroll
    for (int k = 0; k < 6; k++)
      if (ain[k]) gload_lds16(gin[k] + co, (void*)&s_in[din[k]]);
    #pragma unroll
    for (int k = 0; k < 12; k++)
      if (aw[k]) gload_lds16(gw[k] + co, (void*)&s_w[dw[k]]);
    __syncthreads();

    #pragma unroll
    for (int dx = 0; dx < 3; dx++) {
      bf16x8 af[6];
      #pragma unroll
      for (int r = 0; r < 6; r++)
        af[r] = s_in[((wv * 4 + r) * 4 + lq) * 18 + lane15 + dx];
      #pragma unroll
      for (int ky = 0; ky < 3; ky++) {
        int t = ky * 3 + dx;
        bf16x8 bw[5];
        #pragma unroll
        for (int gg = 0; gg < 5; gg++)
          bw[gg] = s_w[(t * 4 + lq) * 81 + gg * 16 + lane15];
        __builtin_amdgcn_s_setprio(1);
        #pragma unroll
        for (int rr = 0; rr < 4; rr++)
          #pragma unroll
          for (int gg = 0; gg < 5; gg++)
            acc[rr][gg] = __builtin_amdgcn_mfma_f32_16x16x32_bf16(
                af[rr + ky], bw[gg], acc[rr][gg], 0, 0, 0);
        __builtin_amdgcn_s_setprio(0);
      }
    }
  }

  // epilogue: fused LSTM pointwise
  int m_hid = nt * 16 + lane15;
  float bi = cb[m_hid], bff = cb[64 + m_hid], bgg = cb[128 + m_hid],
        bo = cb[192 + m_hid], bl = cb[256 + m_hid];
  int xb = x0 + lq * 4;
  size_t chofs = ((size_t)b * 64 + m_hid) * HW;
  #pragma unroll
  for (int rr = 0; rr < 4; rr++) {
    int y = y0 + wv * 4 + rr;
    size_t pofs = chofs + (size_t)y * 64 + xb;
    f32x4 cold = *reinterpret_cast<const f32x4*>(c + pofs);
    f32x4 cn;
    unsigned short ov[4], lv[4];
    #pragma unroll
    for (int e = 0; e < 4; e++) {
      float i_ = sigf(acc[rr][0][e] + bi);
      float f_ = sigf(acc[rr][1][e] + bff);
      float g_ = tanhf(acc[rr][2][e] + bgg);
      float o_ = sigf(acc[rr][3][e] + bo);
      float l_ = sigf(acc[rr][4][e] + bl);
      cn[e] = f_ * cold[e] + i_ * g_;
      ov[e] = f2bfu(o_);
      lv[e] = f2bfu(l_);
    }
    *reinterpret_cast<f32x4*>(c_new + pofs) = cn;
    ushort4 ovv = {ov[0], ov[1], ov[2], ov[3]};
    ushort4 lvv = {lv[0], lv[1], lv[2], lv[3]};
    *reinterpret_cast<ushort4*>(reinterpret_cast<unsigned short*>(o_g) + pofs) = ovv;
    *reinterpret_cast<ushort4*>(reinterpret_cast<unsigned short*>(lam_g) + pofs) = lvv;
  }
}

// ---------------- K7: convfuse 1x1 + tanh + blend -> h_out (2px/thr, co-split 2) -----
__global__ __launch_bounds__(256) void k_fuse(const float* __restrict__ c_new,
    const __hip_bfloat16* __restrict__ mt, const __hip_bfloat16* __restrict__ o_g,
    const __hip_bfloat16* __restrict__ lam_g, const float* __restrict__ h,
    const float* __restrict__ fw, const float* __restrict__ fb,
    float* __restrict__ h_out) {
  __shared__ float wl[112][32];
  int b = blockIdx.y;
  int seg = blockIdx.x & 7, chalf = blockIdx.x >> 3;
  int co0 = chalf * 32;
  for (int i = threadIdx.x; i < 112 * 32; i += 256) {
    int ci = i >> 5, co = i & 31;
    wl[ci][co] = fw[(co0 + co) * 112 + ci];
  }
  __syncthreads();
  int px = seg * 512 + threadIdx.x * 2;
  size_t bofs = (size_t)b * 64 * HW;
  float2 acc[32];
  #pragma unroll
  for (int co = 0; co < 32; co++) { float bv = fb[co0 + co]; acc[co].x = bv; acc[co].y = bv; }
  #pragma unroll 1
  for (int ci = 0; ci < 64; ci++) {
    float2 v = *reinterpret_cast<const float2*>(c_new + bofs + (size_t)ci * HW + px);
    #pragma unroll
    for (int c4 = 0; c4 < 8; c4++) {
      float4 w = *reinterpret_cast<const float4*>(&wl[ci][c4 * 4]);
      acc[c4 * 4 + 0].x += w.x * v.x; acc[c4 * 4 + 0].y += w.x * v.y;
      acc[c4 * 4 + 1].x += w.y * v.x; acc[c4 * 4 + 1].y += w.y * v.y;
      acc[c4 * 4 + 2].x += w.z * v.x; acc[c4 * 4 + 2].y += w.z * v.y;
      acc[c4 * 4 + 3].x += w.w * v.x; acc[c4 * 4 + 3].y += w.w * v.y;
    }
  }
  const unsigned short* mtu = reinterpret_cast<const unsigned short*>(mt);
  size_t mtofs = (size_t)b * MGc * HW + px;
  #pragma unroll 1
  for (int ci = 0; ci < 48; ci++) {
    unsigned u = *reinterpret_cast<const unsigned*>(mtu + mtofs + (size_t)ci * HW);
    float vx = bfu2f((unsigned short)(u & 0xffff));
    float vy = bfu2f((unsigned short)(u >> 16));
    #pragma unroll
    for (int c4 = 0; c4 < 8; c4++) {
      float4 w = *reinterpret_cast<const float4*>(&wl[64 + ci][c4 * 4]);
      acc[c4 * 4 + 0].x += w.x * vx; acc[c4 * 4 + 0].y += w.x * vy;
      acc[c4 * 4 + 1].x += w.y * vx; acc[c4 * 4 + 1].y += w.y * vy;
      acc[c4 * 4 + 2].x += w.z * vx; acc[c4 * 4 + 2].y += w.z * vy;
      acc[c4 * 4 + 3].x += w.w * vx; acc[c4 * 4 + 3].y += w.w * vy;
    }
  }
  const unsigned short* ou = reinterpret_cast<const unsigned short*>(o_g);
  const unsigned short* lu = reinterpret_cast<const unsigned short*>(lam_g);
  #pragma unroll
  for (int co = 0; co < 32; co++) {
    size_t ofs = bofs + (size_t)(co0 + co) * HW + px;
    unsigned uo = *reinterpret_cast<const unsigned*>(ou + ofs);
    unsigned ul = *reinterpret_cast<const unsigned*>(lu + ofs);
    float2 hv = *reinterpret_cast<const float2*>(h + ofs);
    float hnx = tanhf(acc[co].x), hny = tanhf(acc[co].y);
    float ox = bfu2f((unsigned short)(uo & 0xffff)), oy = bfu2f((unsigned short)(uo >> 16));
    float lx = bfu2f((unsigned short)(ul & 0xffff)), ly = bfu2f((unsigned short)(ul >> 16));
    float2 r;
    r.x = lx * (ox * hnx) + (1.f - lx) * hv.x;
    r.y = ly * (oy * hny) + (1.f - ly) * hv.y;
    *reinterpret_cast<float2*>(h_out + ofs) = r;
  }
}

extern "C" void kernel_launch(void* const* d_in, const int* in_sizes, int n_in,
                              void* d_out, int out_size, void* d_ws, size_t ws_size,
                              hipStream_t stream) {
  const float* x   = (const float*)d_in[0];
  const float* h   = (const float*)d_in[1];
  const float* c   = (const float*)d_in[2];
  const float* rm  = (const float*)d_in[3];
  const float* cw  = (const float*)d_in[4];
  const float* cb  = (const float*)d_in[5];
  const float* ccw = (const float*)d_in[6];
  const float* ccb = (const float*)d_in[7];
  const float* sw  = (const float*)d_in[8];
  const float* sb  = (const float*)d_in[9];
  const float* fw  = (const float*)d_in[10];
  const float* fb  = (const float*)d_in[11];

  float* h_out = (float*)d_out;
  float* c_new = h_out + (size_t)16777216;

  // Workspace (lifetime-aliased):
  //   rm_sum [0..61440) + q_part [65536..262144): live k_att -> k_mid only
  //   o_g [0..33554432): born k_gates (ALIASES the above, they're dead)
  //   lam_g [33554432..67108864) | mt [67108864..92274688)
  //   Pp [92274688..163643392) | Wp [163643392..164380672)
  //   mt_pre -> h_out[0..12.6MB): dead after k_ssm, before k_fuse writes h_out.
  char* ws = (char*)d_ws;
  float* rm_sum = (float*)(ws + 0);
  float* q_part = (float*)(ws + 65536);
  __hip_bfloat16* o_g   = (__hip_bfloat16*)(ws + 0);
  __hip_bfloat16* lam_g = (__hip_bfloat16*)(ws + 33554432);
  __hip_bfloat16* mt    = (__hip_bfloat16*)(ws + 67108864);
  __hip_bfloat16* Pp    = (__hip_bfloat16*)(ws + 92274688);
  __hip_bfloat16* Wp    = (__hip_bfloat16*)(ws + 163643392);
  float* mt_pre = h_out;

  k_att<<<16384, 256, 0, stream>>>(rm, rm_sum, c, ccw, ccb, q_part);
  k_mid<<<22960, 256, 0, stream>>>(rm, rm_sum, q_part, mt_pre, cw, Wp, Pp, x, h);
  k_ssm<<<dim3(8, 64), 512, 0, stream>>>(mt_pre, sw, sb, mt);
  k_gates_mfma<<<dim3(64, 64), 256, 0, stream>>>(Pp, Wp, c, cb, c_new, o_g, lam_g);
  k_fuse<<<dim3(16, 64), 256, 0, stream>>>(c_new, mt, o_g, lam_g, h, fw, fb, h_out);
}

// Round 11
// 629.153 us; speedup vs baseline: 1.0502x; 1.0195x over previous
//
#include <hip/hip_runtime.h>
#include <hip/hip_bf16.h>
#include <cstdint>

#define HW 4096
#define MGc 48
#define RECc 5

typedef __attribute__((ext_vector_type(8))) short bf16x8;
typedef __attribute__((ext_vector_type(4))) float f32x4;

__device__ __forceinline__ float sigf(float x) { return 1.f / (1.f + expf(-x)); }
__device__ __forceinline__ float leakyf(float x) { return x >= 0.f ? x : 0.2f * x; }
__device__ __forceinline__ unsigned short f2bfu(float f) {
  __hip_bfloat16 b = __float2bfloat16(f);
  return *reinterpret_cast<unsigned short*>(&b);
}
__device__ __forceinline__ float bfu2f(unsigned short u) {
  unsigned v = ((unsigned)u) << 16;
  return __uint_as_float(v);
}
__device__ __forceinline__ void gload_lds16(const void* g, void* l) {
  __builtin_amdgcn_global_load_lds(
      (const __attribute__((address_space(1))) unsigned int*)g,
      (__attribute__((address_space(3))) unsigned int*)l, 16, 0, 0);
}

// ---------------- L1: k_att = rm_sum [0,15360) + q_part [15360,16384) ----------------
__global__ __launch_bounds__(256) void k_att(const float* __restrict__ rm,
    float* __restrict__ rm_sum, const float* __restrict__ c,
    const float* __restrict__ ccw, const float* __restrict__ ccb,
    float* __restrict__ q_part) {
  __shared__ __align__(16) char smem[13568];
  int bid = blockIdx.x, tid = threadIdx.x;
  if (bid < 15360) {
    float* sred = (float*)smem;
    int row = bid;
    const float4* p = reinterpret_cast<const float4*>(rm + (size_t)row * 1024);
    float4 v = p[tid];
    float s = v.x + v.y + v.z + v.w;
    #pragma unroll
    for (int off = 32; off; off >>= 1) s += __shfl_down(s, off);
    if ((tid & 63) == 0) sred[tid >> 6] = s;
    __syncthreads();
    if (tid == 0) rm_sum[row] = sred[0] + sred[1] + sred[2] + sred[3];
  } else {
    float* wl = (float*)smem;
    float* bl = wl + MGc * 64;
    float (*red)[MGc] = (float(*)[MGc])(bl + 64);
    int r = bid - 15360;
    int seg = r & 15, b = r >> 4;
    for (int i = tid; i < MGc * 64; i += 256) wl[i] = ccw[i];
    if (tid < MGc) bl[tid] = ccb[tid];
    __syncthreads();
    int px = seg * 256 + tid;
    float acc[MGc];
    #pragma unroll
    for (int m = 0; m < MGc; m++) acc[m] = 0.f;
    const float* cp = c + (size_t)b * 64 * HW + px;
    for (int ci = 0; ci < 64; ci++) {
      float v = cp[(size_t)ci * HW];
      #pragma unroll
      for (int m = 0; m < MGc; m++) acc[m] += wl[m * 64 + ci] * v;
    }
    int lane = tid & 63, wv = tid >> 6;
    #pragma unroll
    for (int m = 0; m < MGc; m++) {
      float t2 = leakyf(acc[m] + bl[m]);
      #pragma unroll
      for (int off = 32; off; off >>= 1) t2 += __shfl_down(t2, off);
      if (lane == 0) red[wv][m] = t2;
    }
    __syncthreads();
    if (tid < MGc) {
      float t2 = red[0][tid] + red[1][tid] + red[2][tid] + red[3][tid];
      q_part[((size_t)b * 16 + seg) * MGc + tid] = t2;
    }
  }
}

// ---------------- L2: k_mid = mt_pre [0,12288) + wpack [12288,13728) +
//                  Pp border [13728,14768) + ppack [14768,22960) ----------------
__global__ __launch_bounds__(256) void k_mid(const float* __restrict__ rm,
    const float* __restrict__ rm_sum, const float* __restrict__ q_part,
    float* __restrict__ mt_pre, const float* __restrict__ cw,
    __hip_bfloat16* __restrict__ Wp, __hip_bfloat16* __restrict__ Pp,
    const float* __restrict__ xin, const float* __restrict__ hin) {
  __shared__ __align__(16) char smem[16704];
  int bid = blockIdx.x, tid = threadIdx.x;
  if (bid < 12288) {
    float* sat = (float*)smem;
    int idx = bid * 256 + tid;
    int b = idx / (MGc * 1024);
    if (tid < 64) {
      int lane = tid;
      float q = 0.f;
      if (lane < MGc) {
        float s = 0.f;
        for (int sg = 0; sg < 16; sg++) s += q_part[((size_t)b * 16 + sg) * MGc + lane];
        q = s * (1.f / 4096.f);
      }
      float qs = q * q;
      #pragma unroll
      for (int off = 32; off; off >>= 1) qs += __shfl_xor(qs, off);
      float qn = fmaxf(sqrtf(qs), 1e-8f);
      float cosv[RECc];
      #pragma unroll
      for (int r = 0; r < RECc; r++) {
        float m = 0.f;
        if (lane < MGc) m = rm_sum[((size_t)b * RECc + r) * MGc + lane] * (1.f / 1024.f);
        float d = q * m, ms = m * m;
        #pragma unroll
        for (int off = 32; off; off >>= 1) { d += __shfl_xor(d, off); ms += __shfl_xor(ms, off); }
        float mn = fmaxf(sqrtf(ms), 1e-8f);
        cosv[r] = d / (qn * mn);
      }
      float mx = cosv[0];
      #pragma unroll
      for (int r = 1; r < RECc; r++) mx = fmaxf(mx, cosv[r]);
      float ssum = 0.f;
      #pragma unroll
      for (int r = 0; r < RECc; r++) { cosv[r] = expf(cosv[r] - mx); ssum += cosv[r]; }
      float inv = 1.f / ssum;
      #pragma unroll
      for (int r = 0; r < RECc; r++)
        if (lane == r) sat[r] = cosv[r] * inv;
    }
    __syncthreads();
    int rem = idx - b * (MGc * 1024);
    const float* base = rm + (size_t)b * RECc * MGc * 1024 + rem;
    float v = sat[0] * base[0] + sat[1] * base[MGc * 1024] + sat[2] * base[2 * MGc * 1024]
            + sat[3] * base[3 * MGc * 1024] + sat[4] * base[4 * MGc * 1024];
    mt_pre[idx] = v;
  } else if (bid < 13728) {
    int idx = (bid - 12288) * 256 + tid;
    int t = idx / (320 * 128);
    int rem = idx % (320 * 128);
    int ocp = rem / 128, ci = rem % 128;
    int nt = ocp / 80, r2 = ocp % 80, gate = r2 / 16, ml = r2 % 16;
    int oc = gate * 64 + nt * 16 + ml;
    Wp[idx] = __float2bfloat16(cw[((size_t)oc * 128 + ci) * 9 + t]);
  } else if (bid < 14768) {
    int idx = (bid - 13728) * 256 + tid;
    int b = idx / 4160, i = idx % 4160;
    bf16x8* base = reinterpret_cast<bf16x8*>(Pp);
    size_t u;
    if (i < 2112) {
      int r = (i < 1056) ? 0 : 65;
      int j = (i < 1056) ? i : i - 1056;
      u = ((size_t)b * 66 + r) * 1056 + j;
    } else {
      int i2 = i - 2112;
      int row = 1 + (i2 >> 5), k = i2 & 31;
      int px = (k < 16) ? 0 : 65, ci8 = k & 15;
      u = (((size_t)b * 66 + row) * 66 + px) * 16 + ci8;
    }
    base[u] = (bf16x8)0;
  } else {
    float (*t)[65] = (float(*)[65])smem;
    int r = bid - 14768;
    int half = r & 1, y = (r >> 1) & 63, b = r >> 7;
    const float* src = (half ? hin : xin) + (size_t)b * 64 * HW + y * 64;
    #pragma unroll
    for (int it = 0; it < 4; it++) {
      int li = it * 256 + tid;
      int ci = li >> 4, x4 = (li & 15) * 4;
      float4 v = *reinterpret_cast<const float4*>(src + (size_t)ci * HW + x4);
      t[x4][ci] = v.x; t[x4 + 1][ci] = v.y; t[x4 + 2][ci] = v.z; t[x4 + 3][ci] = v.w;
    }
    __syncthreads();
    int x = tid >> 2, c16 = (tid & 3) * 16;
    unsigned short* dst = reinterpret_cast<unsigned short*>(Pp) +
        ((((size_t)b * 66 + y + 1) * 66 + x + 1) * 128 + half * 64 + c16);
    bf16x8 o0, o1;
    #pragma unroll
    for (int j = 0; j < 8; j++) {
      o0[j] = (short)f2bfu(t[x][c16 + j]);
      o1[j] = (short)f2bfu(t[x][c16 + 8 + j]);
    }
    *reinterpret_cast<bf16x8*>(dst) = o0;
    *reinterpret_cast<bf16x8*>(dst + 8) = o1;
  }
}

// ---------------- K5: conv_transpose2d 4x4 s2 p1 + leaky -> mt (bf16) ----------
__global__ __launch_bounds__(512) void k_ssm(const float* __restrict__ mt_pre,
    const float* __restrict__ w, const float* __restrict__ bias,
    __hip_bfloat16* __restrict__ mt) {
  __shared__ float in_t[12][10][20];
  __shared__ float w_t[12][48][16];
  int b = blockIdx.y;
  int tile = blockIdx.x;
  int y0 = (tile >> 1) * 16, x0 = (tile & 1) * 32;
  int wv = threadIdx.x >> 6, lane = threadIdx.x & 63;
  int co0 = wv * 6;
  int oyl = lane >> 2, xseg = lane & 3;
  int oy = y0 + oyl;
  int iy0 = (y0 >> 1) - 1, ix0 = (x0 >> 1) - 1;
  int kyA = (oy + 1) & 1;
  int iyA = (oy + 1 - kyA) >> 1;
  int rA = iyA - iy0, rB = rA - 1;
  float acc[6][8] = {};
  for (int ch = 0; ch < 4; ch++) {
    int ci0 = ch * 12;
    __syncthreads();
    for (int i = threadIdx.x; i < 12 * 10 * 18; i += 512) {
      int ci = i / 180, rr = (i % 180) / 18, cc2 = i % 18;
      int giy = iy0 + rr, gix = ix0 + cc2;
      float v = 0.f;
      if ((unsigned)giy < 32u && (unsigned)gix < 32u)
        v = mt_pre[(((size_t)b * MGc + ci0 + ci) * 32 + giy) * 32 + gix];
      in_t[ci][rr][cc2] = v;
    }
    for (int i = threadIdx.x; i < 12 * 48 * 16; i += 512)
      (&w_t[0][0][0])[i] = w[ci0 * 768 + i];
    __syncthreads();
    #pragma unroll 1
    for (int ci = 0; ci < 12; ci++) {
      float4 a0 = *reinterpret_cast<const float4*>(&in_t[ci][rA][xseg * 4]);
      float4 a1 = *reinterpret_cast<const float4*>(&in_t[ci][rA][xseg * 4 + 4]);
      float4 b0 = *reinterpret_cast<const float4*>(&in_t[ci][rB][xseg * 4]);
      float4 b1 = *reinterpret_cast<const float4*>(&in_t[ci][rB][xseg * 4 + 4]);
      float vA[6] = {a0.x, a0.y, a0.z, a0.w, a1.x, a1.y};
      float vB[6] = {b0.x, b0.y, b0.z, b0.w, b1.x, b1.y};
      #pragma unroll
      for (int co = 0; co < 6; co++) {
        const float* wp = &w_t[ci][co0 + co][0];
        float4 wA = *reinterpret_cast<const float4*>(wp + kyA * 4);
        float4 wB = *reinterpret_cast<const float4*>(wp + (kyA + 2) * 4);
        #pragma unroll
        for (int j = 0; j < 8; j++) {
          if ((j & 1) == 0) {
            int hi = (j >> 1) + 1, lo = j >> 1;
            acc[co][j] += vA[hi] * wA.y + vA[lo] * wA.w + vB[hi] * wB.y + vB[lo] * wB.w;
          } else {
            int hi = ((j + 1) >> 1) + 1, lo = (j + 1) >> 1;
            acc[co][j] += vA[hi] * wA.x + vA[lo] * wA.z + vB[hi] * wB.x + vB[lo] * wB.z;
          }
        }
      }
    }
  }
  int oxb = x0 + xseg * 8;
  #pragma unroll
  for (int co = 0; co < 6; co++) {
    float bb = bias[co0 + co];
    size_t obase = (((size_t)b * MGc + co0 + co) * 64 + oy) * 64 + oxb;
    #pragma unroll
    for (int j = 0; j < 8; j++)
      mt[obase + j] = __float2bfloat16(leakyf(acc[co][j] + bb));
  }
}

// ---------------- K6: gates conv3x3 MFMA; 4-wave, 3 blocks/CU via s_w tap-split ------
// LDS 51.5KB: s_in (full 32-ci chunk) + s_w[2] (one dx-tap-group each, rotated).
// Per chunk: A: stage s_in+W(dx0) | B: stage W(dx1), comp dx0 | C: stage W(dx2),
// comp dx1 | D: comp dx2. Mid-phase stages hide under compute; head drain 36KB.
__global__ __launch_bounds__(256) void k_gates_mfma(
    const __hip_bfloat16* __restrict__ Pp, const __hip_bfloat16* __restrict__ Wp,
    const float* __restrict__ c, const float* __restrict__ cb,
    float* __restrict__ c_new, __hip_bfloat16* __restrict__ o_g,
    __hip_bfloat16* __restrict__ lam_g) {
  __shared__ bf16x8 s_in[1296];     // (L*4+lq)*18 + xi : 20736 B
  __shared__ bf16x8 s_w[2][960];    // (ky*4+g)*80 + ol : 2 x 15360 B
  int orig = blockIdx.y * gridDim.x + blockIdx.x;
  int t_id = (orig & 7) * 512 + (orig >> 3);   // bijective, 4096 % 8 == 0
  int b = t_id >> 6;
  int r6 = t_id & 63;
  int ytile = r6 >> 4, xtile = (r6 >> 2) & 3, nt = r6 & 3;
  int y0 = ytile * 16, x0 = xtile * 16;
  int tid = threadIdx.x;
  int wv = tid >> 6, lane = tid & 63;
  int lane15 = lane & 15, lq = lane >> 4;

  const char* Pb = (const char*)Pp;
  const char* Wb = (const char*)Wp;

  // ---- precompute staging addresses (cc- and dx-invariant bases) ----
  const char* gin[6]; int din[6]; bool ain[6];
  #pragma unroll
  for (int k = 0; k < 6; k++) {
    int u = wv + 4 * k;
    int e = u * 64 + lane;
    ain[k] = (u < 21) && (e < 1296);
    int ee = (e < 1296) ? e : 0;
    int L = ee / 72, r = ee - L * 72;
    int llq = r / 18, xi = r - llq * 18;
    gin[k] = Pb + ((((size_t)b * 66 + y0 + L) * 66 + (x0 + xi)) * 256) + llq * 16;
    din[k] = ee;
  }
  // one dx-group = 12 rows (ky*4+g) x 80 ol = 960 units = 15 wave-units
  const char* gwb[4]; int dwb[4]; bool awb[4];
  #pragma unroll
  for (int k = 0; k < 4; k++) {
    int u = wv + 4 * k;
    awb[k] = (u < 15);
    int uu = awb[k] ? u : 0;
    int e = uu * 64 + lane;              // [0,960)
    int row = e / 80, ol = e - row * 80;
    int ky = row >> 2, g = row & 3;
    // addr(dx,cc) = base + dx*81920 + cc*64 ; tap t = ky*3+dx
    gwb[k] = Wb + (((size_t)(ky * 3) * 320 + nt * 80 + ol) * 128 + g * 8) * 2;
    dwb[k] = e;
  }

  f32x4 acc[4][5];
  #pragma unroll
  for (int i = 0; i < 4; i++)
    #pragma unroll
    for (int j = 0; j < 5; j++) acc[i][j] = (f32x4)0.f;

#define STAGE_W(BUF, DX, CO) do {                                                     \
    _Pragma("unroll")                                                                 \
    for (int k = 0; k < 4; k++)                                                       \
      if (awb[k]) gload_lds16(gwb[k] + (DX) * 81920 + (CO),                           \
                              (void*)&s_w[BUF][dwb[k]]);                              \
  } while (0)

#define COMP_DX(BUF, DX) do {                                                         \
    bf16x8 af[6];                                                                     \
    _Pragma("unroll")                                                                 \
    for (int r = 0; r < 6; r++)                                                       \
      af[r] = s_in[((wv * 4 + r) * 4 + lq) * 18 + lane15 + (DX)];                     \
    _Pragma("unroll")                                                                 \
    for (int ky = 0; ky < 3; ky++) {                                                  \
      bf16x8 bw[5];                                                                   \
      _Pragma("unroll")                                                               \
      for (int gg = 0; gg < 5; gg++)                                                  \
        bw[gg] = s_w[BUF][(ky * 4 + lq) * 80 + gg * 16 + lane15];                     \
      __builtin_amdgcn_s_setprio(1);                                                  \
      _Pragma("unroll")                                                               \
      for (int rr = 0; rr < 4; rr++)                                                  \
        _Pragma("unroll")                                                             \
        for (int gg = 0; gg < 5; gg++)                                                \
          acc[rr][gg] = __builtin_amdgcn_mfma_f32_16x16x32_bf16(                      \
              af[rr + ky], bw[gg], acc[rr][gg], 0, 0, 0);                             \
      __builtin_amdgcn_s_setprio(0);                                                  \
    }                                                                                 \
  } while (0)

  #pragma unroll 1
  for (int cc = 0; cc < 4; cc++) {
    int co = cc * 64;
    __syncthreads();                     // A: both bufs + s_in free
    #pragma unroll
    for (int k = 0; k < 6; k++)
      if (ain[k]) gload_lds16(gin[k] + co, (void*)&s_in[din[k]]);
    STAGE_W(0, 0, co);
    __syncthreads();                     // B: s_in + dx0 ready
    STAGE_W(1, 1, co);                   // in flight under dx0 compute
    COMP_DX(0, 0);
    __syncthreads();                     // C: dx1 ready; dx0 reads done
    STAGE_W(0, 2, co);                   // in flight under dx1 compute
    COMP_DX(1, 1);
    __syncthreads();                     // D: dx2 ready; dx1 reads done
    COMP_DX(0, 2);
  }
#undef STAGE_W
#undef COMP_DX

  // epilogue: fused LSTM pointwise
  int m_hid = nt * 16 + lane15;
  float bi = cb[m_hid], bff = cb[64 + m_hid], bgg = cb[128 + m_hid],
        bo = cb[192 + m_hid], bl = cb[256 + m_hid];
  int xb = x0 + lq * 4;
  size_t chofs = ((size_t)b * 64 + m_hid) * HW;
  #pragma unroll
  for (int rr = 0; rr < 4; rr++) {
    int y = y0 + wv * 4 + rr;
    size_t pofs = chofs + (size_t)y * 64 + xb;
    f32x4 cold = *reinterpret_cast<const f32x4*>(c + pofs);
    f32x4 cn;
    unsigned short ov[4], lv[4];
    #pragma unroll
    for (int e = 0; e < 4; e++) {
      float i_ = sigf(acc[rr][0][e] + bi);
      float f_ = sigf(acc[rr][1][e] + bff);
      float g_ = tanhf(acc[rr][2][e] + bgg);
      float o_ = sigf(acc[rr][3][e] + bo);
      float l_ = sigf(acc[rr][4][e] + bl);
      cn[e] = f_ * cold[e] + i_ * g_;
      ov[e] = f2bfu(o_);
      lv[e] = f2bfu(l_);
    }
    *reinterpret_cast<f32x4*>(c_new + pofs) = cn;
    ushort4 ovv = {ov[0], ov[1], ov[2], ov[3]};
    ushort4 lvv = {lv[0], lv[1], lv[2], lv[3]};
    *reinterpret_cast<ushort4*>(reinterpret_cast<unsigned short*>(o_g) + pofs) = ovv;
    *reinterpret_cast<ushort4*>(reinterpret_cast<unsigned short*>(lam_g) + pofs) = lvv;
  }
}

// ---------------- K7: convfuse 1x1 + tanh + blend -> h_out (2px/thr, co-split 2) -----
__global__ __launch_bounds__(256) void k_fuse(const float* __restrict__ c_new,
    const __hip_bfloat16* __restrict__ mt, const __hip_bfloat16* __restrict__ o_g,
    const __hip_bfloat16* __restrict__ lam_g, const float* __restrict__ h,
    const float* __restrict__ fw, const float* __restrict__ fb,
    float* __restrict__ h_out) {
  __shared__ float wl[112][32];
  int b = blockIdx.y;
  int seg = blockIdx.x & 7, chalf = blockIdx.x >> 3;
  int co0 = chalf * 32;
  for (int i = threadIdx.x; i < 112 * 32; i += 256) {
    int ci = i >> 5, co = i & 31;
    wl[ci][co] = fw[(co0 + co) * 112 + ci];
  }
  __syncthreads();
  int px = seg * 512 + threadIdx.x * 2;
  size_t bofs = (size_t)b * 64 * HW;
  float2 acc[32];
  #pragma unroll
  for (int co = 0; co < 32; co++) { float bv = fb[co0 + co]; acc[co].x = bv; acc[co].y = bv; }
  #pragma unroll 1
  for (int ci = 0; ci < 64; ci++) {
    float2 v = *reinterpret_cast<const float2*>(c_new + bofs + (size_t)ci * HW + px);
    #pragma unroll
    for (int c4 = 0; c4 < 8; c4++) {
      float4 w = *reinterpret_cast<const float4*>(&wl[ci][c4 * 4]);
      acc[c4 * 4 + 0].x += w.x * v.x; acc[c4 * 4 + 0].y += w.x * v.y;
      acc[c4 * 4 + 1].x += w.y * v.x; acc[c4 * 4 + 1].y += w.y * v.y;
      acc[c4 * 4 + 2].x += w.z * v.x; acc[c4 * 4 + 2].y += w.z * v.y;
      acc[c4 * 4 + 3].x += w.w * v.x; acc[c4 * 4 + 3].y += w.w * v.y;
    }
  }
  const unsigned short* mtu = reinterpret_cast<const unsigned short*>(mt);
  size_t mtofs = (size_t)b * MGc * HW + px;
  #pragma unroll 1
  for (int ci = 0; ci < 48; ci++) {
    unsigned u = *reinterpret_cast<const unsigned*>(mtu + mtofs + (size_t)ci * HW);
    float vx = bfu2f((unsigned short)(u & 0xffff));
    float vy = bfu2f((unsigned short)(u >> 16));
    #pragma unroll
    for (int c4 = 0; c4 < 8; c4++) {
      float4 w = *reinterpret_cast<const float4*>(&wl[64 + ci][c4 * 4]);
      acc[c4 * 4 + 0].x += w.x * vx; acc[c4 * 4 + 0].y += w.x * vy;
      acc[c4 * 4 + 1].x += w.y * vx; acc[c4 * 4 + 1].y += w.y * vy;
      acc[c4 * 4 + 2].x += w.z * vx; acc[c4 * 4 + 2].y += w.z * vy;
      acc[c4 * 4 + 3].x += w.w * vx; acc[c4 * 4 + 3].y += w.w * vy;
    }
  }
  const unsigned short* ou = reinterpret_cast<const unsigned short*>(o_g);
  const unsigned short* lu = reinterpret_cast<const unsigned short*>(lam_g);
  #pragma unroll
  for (int co = 0; co < 32; co++) {
    size_t ofs = bofs + (size_t)(co0 + co) * HW + px;
    unsigned uo = *reinterpret_cast<const unsigned*>(ou + ofs);
    unsigned ul = *reinterpret_cast<const unsigned*>(lu + ofs);
    float2 hv = *reinterpret_cast<const float2*>(h + ofs);
    float hnx = tanhf(acc[co].x), hny = tanhf(acc[co].y);
    float ox = bfu2f((unsigned short)(uo & 0xffff)), oy = bfu2f((unsigned short)(uo >> 16));
    float lx = bfu2f((unsigned short)(ul & 0xffff)), ly = bfu2f((unsigned short)(ul >> 16));
    float2 r;
    r.x = lx * (ox * hnx) + (1.f - lx) * hv.x;
    r.y = ly * (oy * hny) + (1.f - ly) * hv.y;
    *reinterpret_cast<float2*>(h_out + ofs) = r;
  }
}

extern "C" void kernel_launch(void* const* d_in, const int* in_sizes, int n_in,
                              void* d_out, int out_size, void* d_ws, size_t ws_size,
                              hipStream_t stream) {
  const float* x   = (const float*)d_in[0];
  const float* h   = (const float*)d_in[1];
  const float* c   = (const float*)d_in[2];
  const float* rm  = (const float*)d_in[3];
  const float* cw  = (const float*)d_in[4];
  const float* cb  = (const float*)d_in[5];
  const float* ccw = (const float*)d_in[6];
  const float* ccb = (const float*)d_in[7];
  const float* sw  = (const float*)d_in[8];
  const float* sb  = (const float*)d_in[9];
  const float* fw  = (const float*)d_in[10];
  const float* fb  = (const float*)d_in[11];

  float* h_out = (float*)d_out;
  float* c_new = h_out + (size_t)16777216;

  // Workspace (lifetime-aliased):
  //   rm_sum [0..61440) + q_part [65536..262144): live k_att -> k_mid only
  //   o_g [0..33554432): born k_gates (ALIASES the above, they're dead)
  //   lam_g [33554432..67108864) | mt [67108864..92274688)
  //   Pp [92274688..163643392) | Wp [163643392..164380672)
  //   mt_pre -> h_out[0..12.6MB): dead after k_ssm, before k_fuse writes h_out.
  char* ws = (char*)d_ws;
  float* rm_sum = (float*)(ws + 0);
  float* q_part = (float*)(ws + 65536);
  __hip_bfloat16* o_g   = (__hip_bfloat16*)(ws + 0);
  __hip_bfloat16* lam_g = (__hip_bfloat16*)(ws + 33554432);
  __hip_bfloat16* mt    = (__hip_bfloat16*)(ws + 67108864);
  __hip_bfloat16* Pp    = (__hip_bfloat16*)(ws + 92274688);
  __hip_bfloat16* Wp    = (__hip_bfloat16*)(ws + 163643392);
  float* mt_pre = h_out;

  k_att<<<16384, 256, 0, stream>>>(rm, rm_sum, c, ccw, ccb, q_part);
  k_mid<<<22960, 256, 0, stream>>>(rm, rm_sum, q_part, mt_pre, cw, Wp, Pp, x, h);
  k_ssm<<<dim3(8, 64), 512, 0, stream>>>(mt_pre, sw, sb, mt);
  k_gates_mfma<<<dim3(64, 64), 256, 0, stream>>>(Pp, Wp, c, cb, c_new, o_g, lam_g);
  k_fuse<<<dim3(16, 64), 256, 0, stream>>>(c_new, mt, o_g, lam_g, h, fw, fb, h_out);
}